// Round 1
// baseline (15.858 us; speedup 1.0000x reference)
//
#include <hip/hip_runtime.h>

// EmbeddingDropout: out[t,:] = mask[words[t]] * weight[words[t],:]
// weight: [V=50257, D=1024] f32, mask: [V,1] f32, words: [B*S=8192] int32
// out: [8192, 1024] f32.  Pure memory-bound gather (~64 MiB traffic).

#define DIM 1024

__global__ void EmbeddingDropout_kernel(const float* __restrict__ weight,
                                        const float* __restrict__ mask,
                                        const int* __restrict__ words,
                                        float* __restrict__ out,
                                        int n_tokens) {
    // One block per token; 256 threads x float4 = 1024 floats = one row.
    int tok = blockIdx.x;
    if (tok >= n_tokens) return;
    int row = words[tok];                 // wave-uniform (broadcast load)
    float m = mask[row];                  // wave-uniform
    const float4* __restrict__ src =
        reinterpret_cast<const float4*>(weight + (size_t)row * DIM);
    float4* __restrict__ dst =
        reinterpret_cast<float4*>(out + (size_t)tok * DIM);
    float4 v = src[threadIdx.x];
    v.x *= m; v.y *= m; v.z *= m; v.w *= m;
    dst[threadIdx.x] = v;
}

extern "C" void kernel_launch(void* const* d_in, const int* in_sizes, int n_in,
                              void* d_out, int out_size, void* d_ws, size_t ws_size,
                              hipStream_t stream) {
    const float* weight = (const float*)d_in[0];
    const float* mask   = (const float*)d_in[1];
    const int*   words  = (const int*)d_in[2];
    float* out = (float*)d_out;
    int n_tokens = in_sizes[2];           // B*S = 8192

    dim3 grid(n_tokens);
    dim3 block(DIM / 4);                  // 256 threads, one float4 each
    EmbeddingDropout_kernel<<<grid, block, 0, stream>>>(weight, mask, words, out, n_tokens);
}